// Round 10
// baseline (427.350 us; speedup 1.0000x reference)
//
#include <hip/hip_runtime.h>

typedef float  f32x4  __attribute__((ext_vector_type(4)));
typedef short  bf16x8 __attribute__((ext_vector_type(8)));

#define TWOLOG2E   2.8853900817779268f
#define NLOG2E    -1.4426950408889634f
#define NTWOLOG2E -2.8853900817779268f

__device__ __forceinline__ unsigned short f2b(float f) {      // fp32 -> bf16 RNE
    unsigned int u = __builtin_bit_cast(unsigned int, f);
    u += 0x7fffu + ((u >> 16) & 1u);
    return (unsigned short)(u >> 16);
}
__device__ __forceinline__ float b2f(unsigned short s) {
    unsigned int u = ((unsigned int)s) << 16;
    return __builtin_bit_cast(float, u);
}
__device__ __forceinline__ unsigned int pk2(float lo, float hi) {
#if __has_builtin(__builtin_amdgcn_cvt_pk_bf16_f32)
    typedef __bf16 bf16x2 __attribute__((ext_vector_type(2)));
    bf16x2 p = __builtin_amdgcn_cvt_pk_bf16_f32(lo, hi);
    return __builtin_bit_cast(unsigned int, p);
#else
    return (unsigned int)f2b(lo) | ((unsigned int)f2b(hi) << 16);
#endif
}
__device__ __forceinline__ float frcp(float x) { return __builtin_amdgcn_rcpf(x); }
__device__ __forceinline__ float fex2(float x) { return __builtin_amdgcn_exp2f(x); }

// block = 256 thr = 4 waves, 32 rows (grid 512, 2 blocks/CU). DEPTH-2 pipeline:
// wave = (pair P, rowgroup Rg). Pair A (P=0) owns layers 0-1, pair B layers 2-3;
// each wave handles 16 rows (one MFMA M-tile). 32 B-frags (2 layers) live in
// VGPRs, pre-scaled by -log2e (-2log2e for g gate); bias in the MFMA C operand.
// Per superstep (2 timesteps): 4 one-tile cell_steps; intra-pair layer handoff
// and in-superstep recurrence are INTRA-WAVE (lgkm-ordered LDS, no barrier);
// only the A->B interface (h1, parity double-buffered) needs the 1 barrier/superstep
// (33 total). Cell state kept scaled: cp = -2log2e*c, so tanh(c) costs exp2(cp)
// directly. Epilogue per cell: 5 exp + 2 rcp (minimal) + ~14 full-rate.
__global__ __launch_bounds__(256, 2)
void lstm_mfma(const float* __restrict__ xg,  const float* __restrict__ Wih0,
               const float* __restrict__ Wih, const float* __restrict__ Whh,
               const float* __restrict__ bih, const float* __restrict__ bhh,
               const float* __restrict__ Wlin,const float* __restrict__ blin,
               float* __restrict__ out) {
    // shorts, 16-row buffers of 640 (= 16 rows * 40 stride):
    //   h0 [Rg][slot]        @ 0      (4 bufs)   A intra-wave (layer-0 h)
    //   h1 [Rg][par][slot]   @ 2560   (8 bufs)   A -> B interface (layer-1 h)
    //   h2 [Rg][slot]        @ 7680   (4 bufs)   B intra-wave (layer-2 h)
    //   h3 [Rg][slot]        @ 10240  (4 bufs)   B intra-wave + output head
    __shared__ short        hb[12800] __attribute__((aligned(16)));
    __shared__ unsigned int xb[64 * 32];                     // [t][row] 2xbf16

    const int tid  = threadIdx.x;
    const int wv   = __builtin_amdgcn_readfirstlane(tid >> 6);
    const int P    = wv >> 1;          // 0: layers 0-1, 1: layers 2-3 (uniform)
    const int Rg   = wv & 1;           // rowgroup (uniform)
    const int lane = tid & 63;
    const int m    = lane & 15;        // A-row / D-col index
    const int q    = lane >> 4;        // quad
    const int row0 = blockIdx.x * 32;

    for (int i = tid; i < 6400; i += 256) ((unsigned int*)hb)[i] = 0u;

    for (int i = tid; i < 2048; i += 256) {
        int r = i >> 6, t = i & 63;
        float x0 = xg[(size_t)(row0 + r) * 192 + t];
        float x1 = xg[(size_t)(row0 + r) * 192 + 64 + t];
        xb[t * 32 + r] = pk2(x0, x1);
    }

    // ---- one-time gather of B-frags + bias for layers 2P, 2P+1 ----
    // tile g: gate T=g>>1 of unit 2m+(g&1); rowG = T*32 + 2m + (g&1).
    bf16x8 bfr[2][8][2];
    float  bv[2][8];
#pragma unroll
    for (int li = 0; li < 2; ++li) {
        const int l = 2 * P + li;
#pragma unroll
        for (int g = 0; g < 8; ++g) {
            const int   T    = g >> 1;
            const int   rowG = T * 32 + 2 * m + (g & 1);
            const float sc   = (T == 2) ? NTWOLOG2E : NLOG2E;
            bv[li][g] = (bih[l * 128 + rowG] + bhh[l * 128 + rowG]) * sc;
#pragma unroll
            for (int c = 0; c < 2; ++c) {
                const int k0 = c * 32 + q * 8;
                float w[8];
                if (l == 0) {
                    if (c == 0) {
#pragma unroll
                        for (int jj = 0; jj < 8; ++jj) w[jj] = 0.0f;
                        if (q == 0) { w[0] = Wih0[rowG * 2]; w[1] = Wih0[rowG * 2 + 1]; }
                    } else {
                        const float* src = Whh + rowG * 32 + (k0 - 32);
#pragma unroll
                        for (int jj = 0; jj < 8; ++jj) w[jj] = src[jj];
                    }
                } else {
                    const float* src = (c == 0) ? (Wih + (l - 1) * 4096 + rowG * 32 + k0)
                                                : (Whh + l * 4096 + rowG * 32 + (k0 - 32));
#pragma unroll
                    for (int jj = 0; jj < 8; ++jj) w[jj] = src[jj];
                }
                bf16x8 fr;
#pragma unroll
                for (int jj = 0; jj < 8; ++jj) fr[jj] = (short)f2b(w[jj] * sc);
                bfr[li][g][c] = fr;
            }
        }
    }

    float cp[2][2][4];   // scaled cell state: -2log2e * c   [li][hf][r]
#pragma unroll
    for (int li = 0; li < 2; ++li)
#pragma unroll
        for (int hf = 0; hf < 2; ++hf)
#pragma unroll
            for (int r = 0; r < 4; ++r) cp[li][hf][r] = 0.0f;

    short* const h0s0 = hb + Rg * 1280;
    short* const h0s1 = h0s0 + 640;
    short* const h2s0 = hb + 7680 + Rg * 1280;
    short* const h2s1 = h2s0 + 640;
    short* const h3s0 = hb + 10240 + Rg * 1280;
    short* const h3s1 = h3s0 + 640;
    auto h1p = [&](int par, int slot) { return hb + 2560 + ((Rg * 2 + par) * 2 + slot) * 640; };

    __syncthreads();

    // one cell (16 rows, one layer li, one timestep): pinp null => x path (xt)
    auto cell = [&](int li, int xt, const short* pinp, const short* prec, short* pwr) {
        bf16x8 a0, a1;
        if (P == 0 && li == 0) {
            unsigned int xd = xb[xt * 32 + Rg * 16 + m];
            union { unsigned int u[4]; bf16x8 v; } au;
            au.u[0] = (q == 0) ? xd : 0u; au.u[1] = 0u; au.u[2] = 0u; au.u[3] = 0u;
            a0 = au.v;
        } else {
            a0 = *(const bf16x8*)(pinp + m * 40 + q * 8);
        }
        a1 = *(const bf16x8*)(prec + m * 40 + q * 8);

        f32x4 acc[8];
#pragma unroll
        for (int g = 0; g < 8; ++g) {
            f32x4 cb = {bv[li][g], bv[li][g], bv[li][g], bv[li][g]};
            acc[g] = __builtin_amdgcn_mfma_f32_16x16x32_bf16(a0, bfr[li][g][0], cb, 0, 0, 0);
            acc[g] = __builtin_amdgcn_mfma_f32_16x16x32_bf16(a1, bfr[li][g][1], acc[g], 0, 0, 0);
        }
        float h0v[4];
#pragma unroll
        for (int hf = 0; hf < 2; ++hf) {
#pragma unroll
            for (int r = 0; r < 4; ++r) {
                float ei = fex2(acc[0 + hf][r]);          // e^{-a_i}
                float ef = fex2(acc[2 + hf][r]);          // e^{-a_f}
                float eg = fex2(acc[4 + hf][r]);          // e^{-2 a_g}
                float eo = fex2(acc[6 + hf][r]);          // e^{-a_o}
                float ap_f = 1.0f + ef;
                float p1   = (1.0f + ei) * (1.0f + eg);
                float R_   = frcp(p1 * ap_f);
                float egp  = __builtin_fmaf(eg, TWOLOG2E, NTWOLOG2E); // -2log2e*(1-eg)
                float t1   = egp * ap_f;
                float t2   = __builtin_fmaf(cp[li][hf][r], p1, t1);
                float cn   = t2 * R_;                     // scaled cell state
                cp[li][hf][r] = cn;
                float ec = fex2(cn);                      // e^{-2c}
                float Rh = frcp((1.0f + eo) * (1.0f + ec));
                float hh = (1.0f - ec) * Rh;
                if (hf == 0) h0v[r] = hh;
                else ((unsigned int*)pwr)[(q * 4 + r) * 20 + m] = pk2(h0v[r], hh);
            }
        }
    };

    for (int S = 0; S < 33; ++S) {
        const int t0 = 2 * (S - P);           // wave-uniform
        if (t0 >= 0 && t0 <= 62) {
            const int p  = S & 1;
            const int pb = p ^ 1;
            if (P == 0) {
                cell(0, t0,     nullptr,    h0s1,       h0s0);       // l0, t0
                cell(0, t0 + 1, nullptr,    h0s0,       h0s1);       // l0, t1
                cell(1, 0,      h0s0,       h1p(pb, 1), h1p(p, 0));  // l1, t0
                cell(1, 0,      h0s1,       h1p(p, 0),  h1p(p, 1));  // l1, t1
            } else {
                cell(0, 0,      h1p(pb, 0), h2s1,       h2s0);       // l2, t0
                cell(0, 0,      h1p(pb, 1), h2s0,       h2s1);       // l2, t1
                cell(1, 0,      h2s0,       h3s1,       h3s0);       // l3, t0
                cell(1, 0,      h2s1,       h3s0,       h3s1);       // l3, t1
            }
        }
        __syncthreads();
    }

    // output head: h3(t=63) in h3[Rg][slot1]
    if (tid < 32) {
        const short* h3 = hb + 10240 + (tid >> 4) * 1280 + 640 + (tid & 15) * 40;
        float s = blin[0];
#pragma unroll
        for (int k = 0; k < 32; ++k)
            s += Wlin[k] * b2f((unsigned short)h3[k]);
        out[row0 + tid] = frcp(1.0f + fex2(s * NLOG2E));
    }
}

extern "C" void kernel_launch(void* const* d_in, const int* in_sizes, int n_in,
                              void* d_out, int out_size, void* d_ws, size_t ws_size,
                              hipStream_t stream) {
    const float* x    = (const float*)d_in[0];
    const float* Wih0 = (const float*)d_in[1];
    const float* Wih  = (const float*)d_in[2];
    const float* Whh  = (const float*)d_in[3];
    const float* bih  = (const float*)d_in[4];
    const float* bhh  = (const float*)d_in[5];
    const float* Wlin = (const float*)d_in[6];
    const float* blin = (const float*)d_in[7];
    float* out = (float*)d_out;

    lstm_mfma<<<512, 256, 0, stream>>>(x, Wih0, Wih, Whh, bih, bhh, Wlin, blin, out);
}

// Round 11
// 228.149 us; speedup vs baseline: 1.8731x; 1.8731x over previous
//
#include <hip/hip_runtime.h>

typedef float  f32x4  __attribute__((ext_vector_type(4)));
typedef short  bf16x8 __attribute__((ext_vector_type(8)));

#define TWOLOG2E   2.8853900817779268f
#define NLOG2E    -1.4426950408889634f
#define NTWOLOG2E -2.8853900817779268f

__device__ __forceinline__ unsigned short f2b(float f) {      // fp32 -> bf16 RNE
    unsigned int u = __builtin_bit_cast(unsigned int, f);
    u += 0x7fffu + ((u >> 16) & 1u);
    return (unsigned short)(u >> 16);
}
__device__ __forceinline__ float b2f(unsigned short s) {
    unsigned int u = ((unsigned int)s) << 16;
    return __builtin_bit_cast(float, u);
}
__device__ __forceinline__ unsigned int pk2(float lo, float hi) {
#if __has_builtin(__builtin_amdgcn_cvt_pk_bf16_f32)
    typedef __bf16 bf16x2 __attribute__((ext_vector_type(2)));
    bf16x2 p = __builtin_amdgcn_cvt_pk_bf16_f32(lo, hi);
    return __builtin_bit_cast(unsigned int, p);
#else
    return (unsigned int)f2b(lo) | ((unsigned int)f2b(hi) << 16);
#endif
}
__device__ __forceinline__ float frcp(float x) { return __builtin_amdgcn_rcpf(x); }
__device__ __forceinline__ float fex2(float x) { return __builtin_amdgcn_exp2f(x); }

// R9 structure (known 174 us, zero spill) + BARRIER-FREE wave chaining.
// block = 256 thr = 4 waves, 32 rows (grid 512, 2 blocks/CU). Wave l owns layer
// l; 16 B-frags (128 gate-rows x K=64 bf16) live in VGPRs, pre-scaled by -log2e
// (-2log2e for g gate); bias rides the MFMA C operand. h buffers: per layer a
// 4-deep rotation hb[l][t&3] (32row x 40-short A-frag layout). Superstep n =
// timesteps 2n,2n+1; dependencies are PAIRWISE, enforced by LDS progress
// counters + s_sleep spin instead of __syncthreads:
//   forward:  wave l waits prog[l-1] >= n+1  (input h data ready)
//   backward: wave l waits prog[l+1] >= n-1  (slot reuse safe, 1 superstep slack)
// Producer publishes prog[l]=n+1 after s_waitcnt lgkmcnt(0) -> any reader that
// observes the flag also observes the h writes (DS pipe is per-wave in-order).
// Epilogue per cell: 5 exp + 2 rcp (merged-rcp shared-denominator algebra),
// cell state kept pre-scaled (cp = -2log2e*c).
__global__ __launch_bounds__(256, 2)
void lstm_mfma(const float* __restrict__ xg,  const float* __restrict__ Wih0,
               const float* __restrict__ Wih, const float* __restrict__ Whh,
               const float* __restrict__ bih, const float* __restrict__ bhh,
               const float* __restrict__ Wlin,const float* __restrict__ blin,
               float* __restrict__ out) {
    __shared__ short        hb[16 * 1280] __attribute__((aligned(16))); // [l][slot=t&3][32row*40]
    __shared__ unsigned int xb[64 * 32];                                // [t][row] 2xbf16
    __shared__ int          prog[4];

    const int tid  = threadIdx.x;
    const int wv   = __builtin_amdgcn_readfirstlane(tid >> 6);  // layer id, uniform
    const int lane = tid & 63;
    const int m    = lane & 15;    // A-row / D-col index
    const int q    = lane >> 4;    // quad
    const int row0 = blockIdx.x * 32;

    // zero all h slots (t<0 recurrent reads must see 0) + init flags
    for (int i = tid; i < 10240; i += 256) ((unsigned int*)hb)[i] = 0u;
    if (tid < 4) prog[tid] = 0;

    // stage x -> LDS bf16 [t][row]
    for (int i = tid; i < 2048; i += 256) {
        int r = i >> 6, t = i & 63;
        float x0 = xg[(size_t)(row0 + r) * 192 + t];
        float x1 = xg[(size_t)(row0 + r) * 192 + 64 + t];
        xb[t * 32 + r] = pk2(x0, x1);
    }

    // ---- one-time gather of B-frags + bias (negated scales) ----
    // tile g: gate T=g>>1 of unit 2m+(g&1); rowG = T*32 + 2m + (g&1).
    bf16x8 bfr[8][2];
    float  bv[8];
#pragma unroll
    for (int g = 0; g < 8; ++g) {
        const int   T    = g >> 1;
        const int   rowG = T * 32 + 2 * m + (g & 1);
        const float sc   = (T == 2) ? NTWOLOG2E : NLOG2E;
        bv[g] = (bih[wv * 128 + rowG] + bhh[wv * 128 + rowG]) * sc;
#pragma unroll
        for (int c = 0; c < 2; ++c) {
            const int k0 = c * 32 + q * 8;
            float w[8];
            if (wv == 0) {
                if (c == 0) {
#pragma unroll
                    for (int jj = 0; jj < 8; ++jj) w[jj] = 0.0f;
                    if (q == 0) { w[0] = Wih0[rowG * 2]; w[1] = Wih0[rowG * 2 + 1]; }
                } else {
                    const float* src = Whh + rowG * 32 + (k0 - 32);
#pragma unroll
                    for (int jj = 0; jj < 8; ++jj) w[jj] = src[jj];
                }
            } else {
                const float* src = (c == 0) ? (Wih + (wv - 1) * 4096 + rowG * 32 + k0)
                                            : (Whh + wv * 4096 + rowG * 32 + (k0 - 32));
#pragma unroll
                for (int jj = 0; jj < 8; ++jj) w[jj] = src[jj];
            }
            bf16x8 fr;
#pragma unroll
            for (int jj = 0; jj < 8; ++jj) fr[jj] = (short)f2b(w[jj] * sc);
            bfr[g][c] = fr;
        }
    }

    float cp[2][2][4];   // scaled cell state -2log2e*c: [tt][hf][r]
#pragma unroll
    for (int tt = 0; tt < 2; ++tt)
#pragma unroll
        for (int hf = 0; hf < 2; ++hf)
#pragma unroll
            for (int r = 0; r < 4; ++r) cp[tt][hf][r] = 0.0f;

    __syncthreads();   // zeros + x + flags visible to all waves

    // one t cell-step for all 32 rows (2 row-tiles)
    auto cell_step = [&](int t, const short* pa0, const short* pa1, short* hwr) {
        bf16x8 a0[2], a1[2];
#pragma unroll
        for (int tt = 0; tt < 2; ++tt) {
            if (wv == 0) {
                unsigned int xd = xb[t * 32 + tt * 16 + m];
                union { unsigned int u[4]; bf16x8 v; } au;
                au.u[0] = (q == 0) ? xd : 0u; au.u[1] = 0u; au.u[2] = 0u; au.u[3] = 0u;
                a0[tt] = au.v;
            } else {
                a0[tt] = *(const bf16x8*)(pa0 + (tt * 16 + m) * 40 + q * 8);
            }
            a1[tt] = *(const bf16x8*)(pa1 + (tt * 16 + m) * 40 + q * 8);
        }
#pragma unroll
        for (int tt = 0; tt < 2; ++tt) {
            f32x4 acc[8];
#pragma unroll
            for (int g = 0; g < 8; ++g) {
                f32x4 cb = {bv[g], bv[g], bv[g], bv[g]};
                acc[g] = __builtin_amdgcn_mfma_f32_16x16x32_bf16(a0[tt], bfr[g][0], cb, 0, 0, 0);
                acc[g] = __builtin_amdgcn_mfma_f32_16x16x32_bf16(a1[tt], bfr[g][1], acc[g], 0, 0, 0);
            }
            float h0[4];
#pragma unroll
            for (int hf = 0; hf < 2; ++hf) {
#pragma unroll
                for (int r = 0; r < 4; ++r) {
                    float ei = fex2(acc[0 + hf][r]);          // e^{-a_i}
                    float ef = fex2(acc[2 + hf][r]);          // e^{-a_f}
                    float eg = fex2(acc[4 + hf][r]);          // e^{-2 a_g}
                    float eo = fex2(acc[6 + hf][r]);          // e^{-a_o}
                    float ap_f = 1.0f + ef;
                    float p1   = (1.0f + ei) * (1.0f + eg);
                    float R_   = frcp(p1 * ap_f);
                    float egp  = __builtin_fmaf(eg, TWOLOG2E, NTWOLOG2E); // -2log2e*(1-eg)
                    float t1   = egp * ap_f;
                    float t2   = __builtin_fmaf(cp[tt][hf][r], p1, t1);
                    float cn   = t2 * R_;                     // scaled cell state
                    cp[tt][hf][r] = cn;
                    float ec = fex2(cn);                      // e^{-2c}
                    float Rh = frcp((1.0f + eo) * (1.0f + ec));
                    float hh = (1.0f - ec) * Rh;
                    if (hf == 0) h0[r] = hh;
                    else ((unsigned int*)hwr)[(tt * 16 + q * 4 + r) * 20 + m] = pk2(h0[r], hh);
                }
            }
        }
    };

    volatile int* vp = prog;
    short* const myBase = hb + wv * 4 * 1280;
    const short* const inBase = hb + (wv > 0 ? wv - 1 : 0) * 4 * 1280;

    for (int n = 0; n < 32; ++n) {
        // pairwise waits (uniform branches; ds_read same addr = broadcast)
        if (wv > 0) { while (vp[wv - 1] < n + 1) __builtin_amdgcn_s_sleep(1); }
        if (wv < 3) { while (vp[wv + 1] < n - 1) __builtin_amdgcn_s_sleep(1); }
        asm volatile("" ::: "memory");   // don't hoist h reads above the spins

        const int t0 = 2 * n;
        const int s0 = t0 & 3, s1 = (t0 + 1) & 3, sr = (t0 + 3) & 3;
        short*       w0 = myBase + s0 * 1280;
        short*       w1 = myBase + s1 * 1280;
        const short* r0 = myBase + sr * 1280;        // h_l(t0-1)
        const short* i0 = inBase + s0 * 1280;        // h_{l-1}(t0)
        const short* i1 = inBase + s1 * 1280;        // h_{l-1}(t0+1)

        cell_step(t0,     i0, r0, w0);
        cell_step(t0 + 1, i1, w0, w1);

        // publish: h writes committed before the flag (per-wave in-order DS pipe)
        asm volatile("s_waitcnt lgkmcnt(0)" ::: "memory");
        if (lane == 0) vp[wv] = n + 1;
    }

    __syncthreads();   // wave 3's h3(63) visible for the head

    // output head: h3(t=63) at layer 3, slot 63&3 = 3
    if (tid < 32) {
        const short* h3 = hb + (3 * 4 + 3) * 1280 + tid * 40;
        float s = blin[0];
#pragma unroll
        for (int k = 0; k < 32; ++k)
            s += Wlin[k] * b2f((unsigned short)h3[k]);
        out[row0 + tid] = frcp(1.0f + fex2(s * NLOG2E));
    }
}

extern "C" void kernel_launch(void* const* d_in, const int* in_sizes, int n_in,
                              void* d_out, int out_size, void* d_ws, size_t ws_size,
                              hipStream_t stream) {
    const float* x    = (const float*)d_in[0];
    const float* Wih0 = (const float*)d_in[1];
    const float* Wih  = (const float*)d_in[2];
    const float* Whh  = (const float*)d_in[3];
    const float* bih  = (const float*)d_in[4];
    const float* bhh  = (const float*)d_in[5];
    const float* Wlin = (const float*)d_in[6];
    const float* blin = (const float*)d_in[7];
    float* out = (float*)d_out;

    lstm_mfma<<<512, 256, 0, stream>>>(x, Wih0, Wih, Whh, bih, bhh, Wlin, blin, out);
}